// Round 1
// baseline (571.974 us; speedup 1.0000x reference)
//
#include <hip/hip_runtime.h>
#include <hip/hip_bf16.h>

typedef __attribute__((ext_vector_type(4))) float f32x4;
typedef __attribute__((ext_vector_type(8))) short bf16x8;

#define MFMA16(a, b, c) __builtin_amdgcn_mfma_f32_16x16x32_bf16(a, b, c, 0, 0, 0)

constexpr int B_ = 4, S_ = 2048, C_ = 1024, H_ = 16, D_ = 64;
constexpr int M_ = B_ * S_;   // 8192
constexpr int N1_ = 3 * C_;   // 3072
constexpr float NEG = -1e30f;

static __device__ __forceinline__ unsigned short f2b(float f) {
    union { float f; unsigned u; } a; a.f = f;
    unsigned r = a.u + 0x7fffu + ((a.u >> 16) & 1u);
    return (unsigned short)(r >> 16);
}

// ---------------- x fp32 -> bf16 ----------------
__global__ void k_cvt_x(const float* __restrict__ x, unsigned short* __restrict__ xb, int n4) {
    int i = blockIdx.x * blockDim.x + threadIdx.x;
    int stride = gridDim.x * blockDim.x;
    for (; i < n4; i += stride) {
        float4 v = ((const float4*)x)[i];
        ushort4 o;
        o.x = f2b(v.x); o.y = f2b(v.y); o.z = f2b(v.z); o.w = f2b(v.w);
        ((ushort4*)xb)[i] = o;
    }
}

// ---------------- 64x64 transpose+convert tile ----------------
static __device__ void transpose_tile64(const float* __restrict__ src, int sld,
                                        unsigned short* __restrict__ dst, int dld) {
    __shared__ unsigned short T[64][68];
    int tid = threadIdx.x;
#pragma unroll
    for (int rep = 0; rep < 4; ++rep) {
        int r = rep * 16 + (tid >> 4);
        int c = (tid & 15) * 4;
        float4 v = *(const float4*)(src + r * sld + c);
        T[c + 0][r] = f2b(v.x);
        T[c + 1][r] = f2b(v.y);
        T[c + 2][r] = f2b(v.z);
        T[c + 3][r] = f2b(v.w);
    }
    __syncthreads();
#pragma unroll
    for (int rep = 0; rep < 4; ++rep) {
        int r = rep * 16 + (tid >> 4);
        int c = (tid & 15) * 4;
        ushort4 o = *(const ushort4*)(&T[r][c]);
        *(ushort4*)(dst + r * dld + c) = o;
    }
}

// Wq/Wk/Wv [H][C][D] fp32  ->  Wt[n][c] bf16, n = which*1024 + h*64 + d
__global__ void k_pack_qkv(const float* __restrict__ Wq, const float* __restrict__ Wk,
                           const float* __restrict__ Wv, unsigned short* __restrict__ Wt) {
    int ct = blockIdx.x;           // c tile 0..15
    int wh = blockIdx.y;           // 0..47
    int which = wh >> 4, h = wh & 15;
    const float* src = (which == 0 ? Wq : which == 1 ? Wk : Wv) + (size_t)h * C_ * D_ + (size_t)ct * 64 * D_;
    unsigned short* dst = Wt + (size_t)(which * C_ + h * D_) * C_ + ct * 64;
    transpose_tile64(src, D_, dst, C_);
}

// Wp [H*D][C] fp32 -> Wt[c][hd] bf16
__global__ void k_pack_wp(const float* __restrict__ Wp, unsigned short* __restrict__ Wt) {
    int ct = blockIdx.x;           // src col tile (c)
    int rt = blockIdx.y;           // src row tile (hd)
    const float* src = Wp + (size_t)(rt * 64) * C_ + ct * 64;
    unsigned short* dst = Wt + (size_t)(ct * 64) * (H_ * D_) + rt * 64;
    transpose_tile64(src, C_, dst, H_ * D_);
}

// ---------------- GEMM: C[M][N] = A[M][K=1024] * Bt[N][K]^T ----------------
// MODE 0: scatter bf16 into q/k/v [B,H,S,D].  MODE 1: fp32 out + bias.
template <int MODE>
__global__ __launch_bounds__(256, 2) void k_gemm(
    const unsigned short* __restrict__ A, const unsigned short* __restrict__ Bt,
    float* __restrict__ Cout, const float* __restrict__ bias, int N,
    unsigned short* __restrict__ q_out, unsigned short* __restrict__ k_out,
    unsigned short* __restrict__ v_out) {
    constexpr int KD = 1024, BK = 64;
    __shared__ unsigned short As[128][72];
    __shared__ unsigned short Bs[128][72];

    int tid = threadIdx.x;
    int m0 = blockIdx.x * 128;
    int n0 = blockIdx.y * 128;
    int wave = tid >> 6, lane = tid & 63;
    int lg = lane >> 4, lr = lane & 15;
    int wm = (wave >> 1) * 64, wn = (wave & 1) * 64;

    const unsigned short* Ab = A + (size_t)m0 * KD;
    const unsigned short* Bb = Bt + (size_t)n0 * KD;

    f32x4 acc[4][4];
#pragma unroll
    for (int i = 0; i < 4; ++i)
#pragma unroll
        for (int j = 0; j < 4; ++j) acc[i][j] = (f32x4){0.f, 0.f, 0.f, 0.f};

    for (int k0 = 0; k0 < KD; k0 += BK) {
#pragma unroll
        for (int t = 0; t < 4; ++t) {
            int chunk = tid + t * 256;      // 1024 chunks of 16B
            int row = chunk >> 3, part = chunk & 7;
            bf16x8 va = *(const bf16x8*)(Ab + (size_t)row * KD + k0 + part * 8);
            *(bf16x8*)(&As[row][part * 8]) = va;
            bf16x8 vb = *(const bf16x8*)(Bb + (size_t)row * KD + k0 + part * 8);
            *(bf16x8*)(&Bs[row][part * 8]) = vb;
        }
        __syncthreads();
#pragma unroll
        for (int kk = 0; kk < 2; ++kk) {
            bf16x8 af[4], bfr[4];
#pragma unroll
            for (int i = 0; i < 4; ++i) {
                af[i]  = *(const bf16x8*)(&As[wm + i * 16 + lr][kk * 32 + lg * 8]);
                bfr[i] = *(const bf16x8*)(&Bs[wn + i * 16 + lr][kk * 32 + lg * 8]);
            }
#pragma unroll
            for (int i = 0; i < 4; ++i)
#pragma unroll
                for (int j = 0; j < 4; ++j)
                    acc[i][j] = MFMA16(af[i], bfr[j], acc[i][j]);
        }
        __syncthreads();
    }

#pragma unroll
    for (int i = 0; i < 4; ++i) {
#pragma unroll
        for (int j = 0; j < 4; ++j) {
            int ncol = n0 + wn + j * 16 + lr;
#pragma unroll
            for (int r = 0; r < 4; ++r) {
                int m = m0 + wm + i * 16 + lg * 4 + r;
                float val = acc[i][j][r];
                if (MODE == 0) {
                    int which = ncol >> 10, rr = ncol & 1023;
                    int h = rr >> 6, d = rr & 63;
                    int b = m >> 11, s = m & 2047;
                    unsigned short* dst = (which == 0 ? q_out : which == 1 ? k_out : v_out);
                    dst[(((size_t)(b * H_ + h)) * S_ + s) * D_ + d] = f2b(val);
                } else {
                    Cout[(size_t)m * N + ncol] = val + bias[ncol];
                }
            }
        }
    }
}

// ---------------- flash attention (causal) ----------------
// grid: (S/64, B*H), 256 threads (4 waves x 16 q-rows)
__global__ __launch_bounds__(256, 2) void k_attn(
    const unsigned short* __restrict__ Qg, const unsigned short* __restrict__ Kg,
    const unsigned short* __restrict__ Vg, unsigned short* __restrict__ Og) {
    constexpr int LDK = 72;
    __shared__ unsigned short Ks[64][LDK];
    __shared__ unsigned short Vt[64][LDK];   // transposed: Vt[d][t]
    __shared__ unsigned short Pw[4][16][40];

    int tid = threadIdx.x, wave = tid >> 6, lane = tid & 63;
    int lg = lane >> 4, lr = lane & 15;
    int qblk = blockIdx.x, bh = blockIdx.y;
    int b = bh >> 4, h = bh & 15;
    const unsigned short* Qh = Qg + (size_t)bh * S_ * D_;
    const unsigned short* Kh = Kg + (size_t)bh * S_ * D_;
    const unsigned short* Vh = Vg + (size_t)bh * S_ * D_;
    int q0 = qblk * 64;
    int qw = q0 + wave * 16;

    bf16x8 qf[2];
    qf[0] = *(const bf16x8*)(Qh + (size_t)(qw + lr) * D_ + lg * 8);
    qf[1] = *(const bf16x8*)(Qh + (size_t)(qw + lr) * D_ + 32 + lg * 8);

    f32x4 oacc[4];
#pragma unroll
    for (int dt = 0; dt < 4; ++dt) oacc[dt] = (f32x4){0.f, 0.f, 0.f, 0.f};
    float mrow[4], lrow[4];
#pragma unroll
    for (int r = 0; r < 4; ++r) { mrow[r] = NEG; lrow[r] = 0.f; }

    int nchunk = qblk + 1;
    for (int tc = 0; tc < nchunk; ++tc) {
        int t0 = tc * 64;
        // stage K (natural) and V (transposed)
#pragma unroll
        for (int t = 0; t < 2; ++t) {
            int chunk = tid + t * 256;
            int row = chunk >> 3, part = chunk & 7;
            bf16x8 kv = *(const bf16x8*)(Kh + (size_t)(t0 + row) * D_ + part * 8);
            *(bf16x8*)(&Ks[row][part * 8]) = kv;
            bf16x8 vv = *(const bf16x8*)(Vh + (size_t)(t0 + row) * D_ + part * 8);
#pragma unroll
            for (int j = 0; j < 8; ++j) Vt[part * 8 + j][row] = ((unsigned short)vv[j]);
        }
        __syncthreads();

        bool diag = (tc == qblk);
#pragma unroll 1
        for (int sub = 0; sub < 2; ++sub) {
            // ---- scores: two 16x16 tiles over t
            f32x4 sacc[2];
#pragma unroll
            for (int tt = 0; tt < 2; ++tt) {
                f32x4 s = (f32x4){0.f, 0.f, 0.f, 0.f};
#pragma unroll
                for (int dk = 0; dk < 2; ++dk) {
                    bf16x8 kf = *(const bf16x8*)(&Ks[sub * 32 + tt * 16 + lr][dk * 32 + lg * 8]);
                    s = MFMA16(qf[dk], kf, s);
                }
                sacc[tt] = s;
            }
            // ---- scale + mask + online softmax
            float pv[2][4], tmax[4];
#pragma unroll
            for (int r = 0; r < 4; ++r) tmax[r] = NEG;
#pragma unroll
            for (int tt = 0; tt < 2; ++tt)
#pragma unroll
                for (int r = 0; r < 4; ++r) {
                    float sv = sacc[tt][r] * 0.125f;
                    int tcol = t0 + sub * 32 + tt * 16 + lr;
                    int qrow = qw + lg * 4 + r;
                    if (diag && tcol > qrow) sv = NEG;
                    pv[tt][r] = sv;
                    tmax[r] = fmaxf(tmax[r], sv);
                }
#pragma unroll
            for (int off = 1; off < 16; off <<= 1)
#pragma unroll
                for (int r = 0; r < 4; ++r)
                    tmax[r] = fmaxf(tmax[r], __shfl_xor(tmax[r], off));

            float resc[4], rsum[4];
#pragma unroll
            for (int r = 0; r < 4; ++r) {
                float mnew = fmaxf(mrow[r], tmax[r]);
                resc[r] = __expf(mrow[r] - mnew);
                mrow[r] = mnew;
                float sum = 0.f;
#pragma unroll
                for (int tt = 0; tt < 2; ++tt) {
                    float p = __expf(pv[tt][r] - mnew);
                    pv[tt][r] = p;
                    sum += p;
                }
                rsum[r] = sum;
            }
#pragma unroll
            for (int off = 1; off < 16; off <<= 1)
#pragma unroll
                for (int r = 0; r < 4; ++r) rsum[r] += __shfl_xor(rsum[r], off);
#pragma unroll
            for (int r = 0; r < 4; ++r) lrow[r] = lrow[r] * resc[r] + rsum[r];
            // rescale O
#pragma unroll
            for (int dt = 0; dt < 4; ++dt)
#pragma unroll
                for (int r = 0; r < 4; ++r) oacc[dt][r] *= resc[r];

            // ---- P -> LDS (per-wave), then PV
#pragma unroll
            for (int tt = 0; tt < 2; ++tt)
#pragma unroll
                for (int r = 0; r < 4; ++r)
                    Pw[wave][lg * 4 + r][tt * 16 + lr] = f2b(pv[tt][r]);
            asm volatile("s_waitcnt lgkmcnt(0)" ::: "memory");

            bf16x8 pf = *(const bf16x8*)(&Pw[wave][lr][lg * 8]);
#pragma unroll
            for (int dt = 0; dt < 4; ++dt) {
                bf16x8 vf = *(const bf16x8*)(&Vt[dt * 16 + lr][sub * 32 + lg * 8]);
                oacc[dt] = MFMA16(pf, vf, oacc[dt]);
            }
        }
        __syncthreads();
    }

    // epilogue: divide by l, store [B,S,H*D]
#pragma unroll
    for (int dt = 0; dt < 4; ++dt)
#pragma unroll
        for (int r = 0; r < 4; ++r) {
            float o = oacc[dt][r] / lrow[r];
            int s = qw + lg * 4 + r;
            int d = dt * 16 + lr;
            Og[((size_t)(b * S_ + s)) * (H_ * D_) + h * D_ + d] = f2b(o);
        }
}

// ---------------- launcher ----------------
extern "C" void kernel_launch(void* const* d_in, const int* in_sizes, int n_in,
                              void* d_out, int out_size, void* d_ws, size_t ws_size,
                              hipStream_t stream) {
    const float* x  = (const float*)d_in[0];
    const float* Wq = (const float*)d_in[1];
    const float* Wk = (const float*)d_in[2];
    const float* Wv = (const float*)d_in[3];
    const float* Wp = (const float*)d_in[4];
    const float* bp = (const float*)d_in[5];
    float* out = (float*)d_out;

    char* ws = (char*)d_ws;
    size_t off = 0;
    unsigned short* Xbf   = (unsigned short*)(ws + off); off += (size_t)M_ * C_ * 2;        // 16 MB
    unsigned short* Wtqkv = (unsigned short*)(ws + off); off += (size_t)N1_ * C_ * 2;       // 6 MB
    unsigned short* Wtp   = (unsigned short*)(ws + off); off += (size_t)C_ * C_ * 2;        // 2 MB
    unsigned short* Qb    = (unsigned short*)(ws + off); off += (size_t)M_ * C_ * 2;        // 16 MB
    unsigned short* Kb    = (unsigned short*)(ws + off); off += (size_t)M_ * C_ * 2;        // 16 MB
    unsigned short* Vb    = (unsigned short*)(ws + off); off += (size_t)M_ * C_ * 2;        // 16 MB
    unsigned short* AO    = (unsigned short*)(ws + off); off += (size_t)M_ * C_ * 2;        // 16 MB

    k_cvt_x<<<dim3(2048), dim3(256), 0, stream>>>(x, Xbf, M_ * C_ / 4);
    k_pack_qkv<<<dim3(16, 48), dim3(256), 0, stream>>>(Wq, Wk, Wv, Wtqkv);
    k_pack_wp<<<dim3(16, 16), dim3(256), 0, stream>>>(Wp, Wtp);

    k_gemm<0><<<dim3(M_ / 128, N1_ / 128), dim3(256), 0, stream>>>(
        Xbf, Wtqkv, nullptr, nullptr, N1_, Qb, Kb, Vb);

    k_attn<<<dim3(S_ / 64, B_ * H_), dim3(256), 0, stream>>>(Qb, Kb, Vb, AO);

    k_gemm<1><<<dim3(M_ / 128, C_ / 128), dim3(256), 0, stream>>>(
        AO, Wtp, out, bp, C_, nullptr, nullptr, nullptr);
}

// Round 3
// 323.527 us; speedup vs baseline: 1.7679x; 1.7679x over previous
//
#include <hip/hip_runtime.h>
#include <hip/hip_bf16.h>

typedef __attribute__((ext_vector_type(4))) float f32x4;
typedef __attribute__((ext_vector_type(16))) float f32x16;
typedef __attribute__((ext_vector_type(8))) short bf16x8;
typedef __attribute__((ext_vector_type(4))) int i32x4;

#define MFMA16(a, b, c) __builtin_amdgcn_mfma_f32_16x16x32_bf16(a, b, c, 0, 0, 0)
#define MFMA32(a, b, c) __builtin_amdgcn_mfma_f32_32x32x16_bf16(a, b, c, 0, 0, 0)

constexpr int B_ = 4, S_ = 2048, C_ = 1024, H_ = 16, D_ = 64;
constexpr int M_ = B_ * S_;   // 8192
constexpr int N1_ = 3 * C_;   // 3072
constexpr float NEG = -1e30f;
constexpr float L2E = 1.4426950408889634f;

static __device__ __forceinline__ unsigned short f2b(float f) {
    union { float f; unsigned u; } a; a.f = f;
    unsigned r = a.u + 0x7fffu + ((a.u >> 16) & 1u);
    return (unsigned short)(r >> 16);
}

// ---------------- x fp32 -> bf16 ----------------
__global__ void k_cvt_x(const float* __restrict__ x, unsigned short* __restrict__ xb, int n4) {
    int i = blockIdx.x * blockDim.x + threadIdx.x;
    int stride = gridDim.x * blockDim.x;
    for (; i < n4; i += stride) {
        float4 v = ((const float4*)x)[i];
        ushort4 o;
        o.x = f2b(v.x); o.y = f2b(v.y); o.z = f2b(v.z); o.w = f2b(v.w);
        ((ushort4*)xb)[i] = o;
    }
}

// ---------------- 64x64 transpose+convert tile ----------------
static __device__ void transpose_tile64(const float* __restrict__ src, int sld,
                                        unsigned short* __restrict__ dst, int dld) {
    __shared__ unsigned short T[64][68];
    int tid = threadIdx.x;
#pragma unroll
    for (int rep = 0; rep < 4; ++rep) {
        int r = rep * 16 + (tid >> 4);
        int c = (tid & 15) * 4;
        float4 v = *(const float4*)(src + r * sld + c);
        T[c + 0][r] = f2b(v.x);
        T[c + 1][r] = f2b(v.y);
        T[c + 2][r] = f2b(v.z);
        T[c + 3][r] = f2b(v.w);
    }
    __syncthreads();
#pragma unroll
    for (int rep = 0; rep < 4; ++rep) {
        int r = rep * 16 + (tid >> 4);
        int c = (tid & 15) * 4;
        ushort4 o = *(const ushort4*)(&T[r][c]);
        *(ushort4*)(dst + r * dld + c) = o;
    }
}

// Wq/Wk/Wv [H][C][D] fp32  ->  Wt[n][c] bf16, n = which*1024 + h*64 + d
__global__ void k_pack_qkv(const float* __restrict__ Wq, const float* __restrict__ Wk,
                           const float* __restrict__ Wv, unsigned short* __restrict__ Wt) {
    int ct = blockIdx.x;           // c tile 0..15
    int wh = blockIdx.y;           // 0..47
    int which = wh >> 4, h = wh & 15;
    const float* src = (which == 0 ? Wq : which == 1 ? Wk : Wv) + (size_t)h * C_ * D_ + (size_t)ct * 64 * D_;
    unsigned short* dst = Wt + (size_t)(which * C_ + h * D_) * C_ + ct * 64;
    transpose_tile64(src, D_, dst, C_);
}

// Wp [H*D][C] fp32 -> Wt[c][hd] bf16
__global__ void k_pack_wp(const float* __restrict__ Wp, unsigned short* __restrict__ Wt) {
    int ct = blockIdx.x;           // src col tile (c)
    int rt = blockIdx.y;           // src row tile (hd)
    const float* src = Wp + (size_t)(rt * 64) * C_ + ct * 64;
    unsigned short* dst = Wt + (size_t)(ct * 64) * (H_ * D_) + rt * 64;
    transpose_tile64(src, C_, dst, H_ * D_);
}

// ---------------- GEMM: C[M][N] = A[M][K=1024] * Bt[N][K]^T ----------------
// MODE 0: scatter bf16 into q/k/v [B,H,S,D] (q scaled by 0.125).  MODE 1: fp32 out + bias.
template <int MODE>
__global__ __launch_bounds__(256, 2) void k_gemm(
    const unsigned short* __restrict__ A, const unsigned short* __restrict__ Bt,
    float* __restrict__ Cout, const float* __restrict__ bias, int N,
    unsigned short* __restrict__ q_out, unsigned short* __restrict__ k_out,
    unsigned short* __restrict__ v_out) {
    constexpr int KD = 1024, BK = 64;
    __shared__ unsigned short As[128][72];
    __shared__ unsigned short Bs[128][72];

    int tid = threadIdx.x;
    int m0 = blockIdx.x * 128;
    int n0 = blockIdx.y * 128;
    int wave = tid >> 6, lane = tid & 63;
    int lg = lane >> 4, lr = lane & 15;
    int wm = (wave >> 1) * 64, wn = (wave & 1) * 64;

    const unsigned short* Ab = A + (size_t)m0 * KD;
    const unsigned short* Bb = Bt + (size_t)n0 * KD;

    f32x4 acc[4][4];
#pragma unroll
    for (int i = 0; i < 4; ++i)
#pragma unroll
        for (int j = 0; j < 4; ++j) acc[i][j] = (f32x4){0.f, 0.f, 0.f, 0.f};

    for (int k0 = 0; k0 < KD; k0 += BK) {
#pragma unroll
        for (int t = 0; t < 4; ++t) {
            int chunk = tid + t * 256;      // 1024 chunks of 16B
            int row = chunk >> 3, part = chunk & 7;
            bf16x8 va = *(const bf16x8*)(Ab + (size_t)row * KD + k0 + part * 8);
            *(bf16x8*)(&As[row][part * 8]) = va;
            bf16x8 vb = *(const bf16x8*)(Bb + (size_t)row * KD + k0 + part * 8);
            *(bf16x8*)(&Bs[row][part * 8]) = vb;
        }
        __syncthreads();
#pragma unroll
        for (int kk = 0; kk < 2; ++kk) {
            bf16x8 af[4], bfr[4];
#pragma unroll
            for (int i = 0; i < 4; ++i) {
                af[i]  = *(const bf16x8*)(&As[wm + i * 16 + lr][kk * 32 + lg * 8]);
                bfr[i] = *(const bf16x8*)(&Bs[wn + i * 16 + lr][kk * 32 + lg * 8]);
            }
#pragma unroll
            for (int i = 0; i < 4; ++i)
#pragma unroll
                for (int j = 0; j < 4; ++j)
                    acc[i][j] = MFMA16(af[i], bfr[j], acc[i][j]);
        }
        __syncthreads();
    }

#pragma unroll
    for (int i = 0; i < 4; ++i) {
#pragma unroll
        for (int j = 0; j < 4; ++j) {
            int ncol = n0 + wn + j * 16 + lr;
#pragma unroll
            for (int r = 0; r < 4; ++r) {
                int m = m0 + wm + i * 16 + lg * 4 + r;
                float val = acc[i][j][r];
                if (MODE == 0) {
                    int which = ncol >> 10, rr = ncol & 1023;
                    int h = rr >> 6, d = rr & 63;
                    int b = m >> 11, s = m & 2047;
                    if (which == 0) val *= 0.125f;   // fold attn scale into Q
                    unsigned short* dst = (which == 0 ? q_out : which == 1 ? k_out : v_out);
                    dst[(((size_t)(b * H_ + h)) * S_ + s) * D_ + d] = f2b(val);
                } else {
                    Cout[(size_t)m * N + ncol] = val + bias[ncol];
                }
            }
        }
    }
}

// ---------------- flash attention (causal), 8 warps x 32 q-rows, KVBLK=64 ----------------
// Swapped QK^T: S^T = K*Q^T via mfma_32x32x16 -> lane owns one q column.
// PV as O^T = V^T * P^T -> rescale is lane-local. P never leaves registers.
__global__ __launch_bounds__(512, 2) void k_attn(
    const unsigned short* __restrict__ Qg, const unsigned short* __restrict__ Kg,
    const unsigned short* __restrict__ Vg, unsigned short* __restrict__ Og) {
    union SMem {
        struct {
            unsigned short k[64][72];     // K natural [t][d], row pad 8
            unsigned short v[4672];       // V^T gap layout: off(d)=d*72+(d>>3)*8, col t
        } st;
        unsigned short oe[8][32][72];     // epilogue O staging per warp
    };
    __shared__ SMem sm;

    const int tid = threadIdx.x;
    const int wid = tid >> 6, lane = tid & 63;
    const int ql = lane & 31, hv = lane >> 5;
    const int qtile = blockIdx.x, bh = blockIdx.y;
    const int b = bh >> 4, hh = bh & 15;
    const unsigned short* Qh = Qg + (size_t)bh * S_ * D_;
    const unsigned short* Kh = Kg + (size_t)bh * S_ * D_;
    const unsigned short* Vh = Vg + (size_t)bh * S_ * D_;
    const int q0 = qtile * 256;
    const int qw = q0 + wid * 32;
    const int qglob = qw + ql;

    // Q fragments (B-operand): lane ql = q col, k elems d = dk*16 + hv*8 + j
    bf16x8 qf[4];
#pragma unroll
    for (int dk = 0; dk < 4; ++dk)
        qf[dk] = *(const bf16x8*)(Qh + (size_t)(qw + ql) * D_ + dk * 16 + hv * 8);

    f32x16 oacc[2];
#pragma unroll
    for (int i = 0; i < 16; ++i) { oacc[0][i] = 0.f; oacc[1][i] = 0.f; }
    float m2 = NEG, lsum = 0.f;

    const int ntiles = qtile * 4 + 4;
    for (int tc = 0; tc < ntiles; ++tc) {
        const int t0 = tc * 64;
        // ---- stage K natural + V transposed (gap layout) : 512 threads, one pass
        {
            const int row = tid >> 3, part = tid & 7;
            bf16x8 kv = *(const bf16x8*)(Kh + (size_t)(t0 + row) * D_ + part * 8);
            *(bf16x8*)(&sm.st.k[row][part * 8]) = kv;
            bf16x8 vv = *(const bf16x8*)(Vh + (size_t)(t0 + row) * D_ + part * 8);
#pragma unroll
            for (int j = 0; j < 8; ++j) {
                int d = part * 8 + j;
                sm.st.v[d * 72 + part * 8 + row] = (unsigned short)vv[j];
            }
        }
        __syncthreads();

        if (t0 < qw + 32) {
            // ---- S^T = K · Q^T  (two 32x32 t-subtiles)
            f32x16 st[2];
#pragma unroll
            for (int ts = 0; ts < 2; ++ts) {
#pragma unroll
                for (int i = 0; i < 16; ++i) st[ts][i] = 0.f;
#pragma unroll
                for (int dk = 0; dk < 4; ++dk) {
                    bf16x8 kf = *(const bf16x8*)(&sm.st.k[ts * 32 + ql][dk * 16 + hv * 8]);
                    st[ts] = MFMA32(kf, qf[dk], st[ts]);
                }
            }
            // ---- online softmax in log2 domain; everything lane-local per q
            const bool diag = (t0 + 63 > qw);
            float z[32];
            float mt = NEG;
#pragma unroll
            for (int ts = 0; ts < 2; ++ts)
#pragma unroll
                for (int r = 0; r < 16; ++r) {
                    float v = st[ts][r] * L2E;
                    if (diag) {
                        int tg = t0 + ts * 32 + (r & 3) + 8 * (r >> 2) + 4 * hv;
                        if (tg > qglob) v = NEG;
                    }
                    z[ts * 16 + r] = v;
                    mt = fmaxf(mt, v);
                }
            mt = fmaxf(mt, __shfl_xor(mt, 32));
            float mnew = fmaxf(m2, mt);
            float resc = exp2f(m2 - mnew);
            m2 = mnew;
            float rs = 0.f;
#pragma unroll
            for (int i = 0; i < 32; ++i) {
                float p = exp2f(z[i] - mnew);
                z[i] = p;
                rs += p;
            }
            rs += __shfl_xor(rs, 32);
            lsum = lsum * resc + rs;
#pragma unroll
            for (int i = 0; i < 16; ++i) { oacc[0][i] *= resc; oacc[1][i] *= resc; }

            // ---- P -> bf16 fragments (cvt_pk + lane^32 exchange), then PV
#pragma unroll
            for (int ts = 0; ts < 2; ++ts) {
#pragma unroll
                for (int sl = 0; sl < 2; ++sl) {
                    unsigned w0, w1, w2, w3;
                    asm("v_cvt_pk_bf16_f32 %0, %1, %2" : "=v"(w0) : "v"(z[ts * 16 + sl * 8 + 0]), "v"(z[ts * 16 + sl * 8 + 1]));
                    asm("v_cvt_pk_bf16_f32 %0, %1, %2" : "=v"(w1) : "v"(z[ts * 16 + sl * 8 + 2]), "v"(z[ts * 16 + sl * 8 + 3]));
                    asm("v_cvt_pk_bf16_f32 %0, %1, %2" : "=v"(w2) : "v"(z[ts * 16 + sl * 8 + 4]), "v"(z[ts * 16 + sl * 8 + 5]));
                    asm("v_cvt_pk_bf16_f32 %0, %1, %2" : "=v"(w3) : "v"(z[ts * 16 + sl * 8 + 6]), "v"(z[ts * 16 + sl * 8 + 7]));
                    unsigned x0 = (unsigned)__shfl_xor((int)w0, 32);
                    unsigned x1 = (unsigned)__shfl_xor((int)w1, 32);
                    unsigned x2 = (unsigned)__shfl_xor((int)w2, 32);
                    unsigned x3 = (unsigned)__shfl_xor((int)w3, 32);
                    i32x4 fw;
                    fw[0] = (int)(hv ? x2 : w0);
                    fw[1] = (int)(hv ? x3 : w1);
                    fw[2] = (int)(hv ? w2 : x0);
                    fw[3] = (int)(hv ? w3 : x1);
                    bf16x8 pf = __builtin_bit_cast(bf16x8, fw);
                    const int slice = ts * 2 + sl;   // 16-wide t slice within KV tile
#pragma unroll
                    for (int dt = 0; dt < 2; ++dt) {
                        int d = dt * 32 + ql;
                        bf16x8 vf = *(const bf16x8*)(&sm.st.v[d * 72 + (d >> 3) * 8 + slice * 16 + hv * 8]);
                        oacc[dt] = MFMA32(vf, pf, oacc[dt]);
                    }
                }
            }
        }
        __syncthreads();
    }

    // ---- epilogue: O^T regs -> LDS -> coalesced global store [B,S,H*D]
    float inv = 1.f / lsum;
#pragma unroll
    for (int dt = 0; dt < 2; ++dt)
#pragma unroll
        for (int r = 0; r < 16; ++r) {
            int d = dt * 32 + (r & 3) + 8 * (r >> 2) + 4 * hv;
            sm.oe[wid][ql][d] = f2b(oacc[dt][r] * inv);
        }
    __syncthreads();
    {
        const int r = tid >> 1, half = tid & 1;
        const int w = r >> 5, q = r & 31;
        unsigned short* dst = Og + ((size_t)(b * S_ + q0 + r)) * (H_ * D_) + hh * D_ + half * 32;
#pragma unroll
        for (int i = 0; i < 4; ++i) {
            bf16x8 v = *(const bf16x8*)(&sm.oe[w][q][half * 32 + i * 8]);
            *(bf16x8*)(dst + i * 8) = v;
        }
    }
}

// ---------------- launcher ----------------
extern "C" void kernel_launch(void* const* d_in, const int* in_sizes, int n_in,
                              void* d_out, int out_size, void* d_ws, size_t ws_size,
                              hipStream_t stream) {
    const float* x  = (const float*)d_in[0];
    const float* Wq = (const float*)d_in[1];
    const float* Wk = (const float*)d_in[2];
    const float* Wv = (const float*)d_in[3];
    const float* Wp = (const float*)d_in[4];
    const float* bp = (const float*)d_in[5];
    float* out = (float*)d_out;

    char* ws = (char*)d_ws;
    size_t off = 0;
    unsigned short* Xbf   = (unsigned short*)(ws + off); off += (size_t)M_ * C_ * 2;        // 16 MB
    unsigned short* Wtqkv = (unsigned short*)(ws + off); off += (size_t)N1_ * C_ * 2;       // 6 MB
    unsigned short* Wtp   = (unsigned short*)(ws + off); off += (size_t)C_ * C_ * 2;        // 2 MB
    unsigned short* Qb    = (unsigned short*)(ws + off); off += (size_t)M_ * C_ * 2;        // 16 MB
    unsigned short* Kb    = (unsigned short*)(ws + off); off += (size_t)M_ * C_ * 2;        // 16 MB
    unsigned short* Vb    = (unsigned short*)(ws + off); off += (size_t)M_ * C_ * 2;        // 16 MB
    unsigned short* AO    = (unsigned short*)(ws + off); off += (size_t)M_ * C_ * 2;        // 16 MB

    k_cvt_x<<<dim3(2048), dim3(256), 0, stream>>>(x, Xbf, M_ * C_ / 4);
    k_pack_qkv<<<dim3(16, 48), dim3(256), 0, stream>>>(Wq, Wk, Wv, Wtqkv);
    k_pack_wp<<<dim3(16, 16), dim3(256), 0, stream>>>(Wp, Wtp);

    k_gemm<0><<<dim3(M_ / 128, N1_ / 128), dim3(256), 0, stream>>>(
        Xbf, Wtqkv, nullptr, nullptr, N1_, Qb, Kb, Vb);

    k_attn<<<dim3(S_ / 256, B_ * H_), dim3(512), 0, stream>>>(Qb, Kb, Vb, AO);

    k_gemm<1><<<dim3(M_ / 128, C_ / 128), dim3(256), 0, stream>>>(
        AO, Wtp, out, bp, C_, nullptr, nullptr, nullptr);
}

// Round 5
// 298.650 us; speedup vs baseline: 1.9152x; 1.0833x over previous
//
#include <hip/hip_runtime.h>
#include <hip/hip_bf16.h>

typedef __attribute__((ext_vector_type(4))) float f32x4;
typedef __attribute__((ext_vector_type(16))) float f32x16;
typedef __attribute__((ext_vector_type(8))) short bf16x8;
typedef __attribute__((ext_vector_type(4))) int i32x4;

#define MFMA16(a, b, c) __builtin_amdgcn_mfma_f32_16x16x32_bf16(a, b, c, 0, 0, 0)
#define MFMA32(a, b, c) __builtin_amdgcn_mfma_f32_32x32x16_bf16(a, b, c, 0, 0, 0)

constexpr int B_ = 4, S_ = 2048, C_ = 1024, H_ = 16, D_ = 64;
constexpr int M_ = B_ * S_;   // 8192
constexpr int N1_ = 3 * C_;   // 3072
constexpr float NEG = -1e30f;
constexpr float L2E = 1.4426950408889634f;

static __device__ __forceinline__ unsigned short f2b(float f) {
    union { float f; unsigned u; } a; a.f = f;
    unsigned r = a.u + 0x7fffu + ((a.u >> 16) & 1u);
    return (unsigned short)(r >> 16);
}

// async global -> LDS, 16 bytes per lane. dst must be wave-uniform; HW adds lane*16.
static __device__ __forceinline__ void gload_lds16(const void* g, void* l) {
    __builtin_amdgcn_global_load_lds(
        (const __attribute__((address_space(1))) unsigned int*)g,
        (__attribute__((address_space(3))) unsigned int*)l, 16, 0, 0);
}

// ---------------- x fp32 -> bf16 ----------------
__global__ void k_cvt_x(const float* __restrict__ x, unsigned short* __restrict__ xb, int n4) {
    int i = blockIdx.x * blockDim.x + threadIdx.x;
    int stride = gridDim.x * blockDim.x;
    for (; i < n4; i += stride) {
        float4 v = ((const float4*)x)[i];
        ushort4 o;
        o.x = f2b(v.x); o.y = f2b(v.y); o.z = f2b(v.z); o.w = f2b(v.w);
        ((ushort4*)xb)[i] = o;
    }
}

// ---------------- 64x64 transpose+convert tile ----------------
static __device__ void transpose_tile64(const float* __restrict__ src, int sld,
                                        unsigned short* __restrict__ dst, int dld) {
    __shared__ unsigned short T[64][68];
    int tid = threadIdx.x;
#pragma unroll
    for (int rep = 0; rep < 4; ++rep) {
        int r = rep * 16 + (tid >> 4);
        int c = (tid & 15) * 4;
        float4 v = *(const float4*)(src + r * sld + c);
        T[c + 0][r] = f2b(v.x);
        T[c + 1][r] = f2b(v.y);
        T[c + 2][r] = f2b(v.z);
        T[c + 3][r] = f2b(v.w);
    }
    __syncthreads();
#pragma unroll
    for (int rep = 0; rep < 4; ++rep) {
        int r = rep * 16 + (tid >> 4);
        int c = (tid & 15) * 4;
        ushort4 o = *(const ushort4*)(&T[r][c]);
        *(ushort4*)(dst + r * dld + c) = o;
    }
}

// Wq/Wk/Wv [H][C][D] fp32  ->  Wt[n][c] bf16, n = which*1024 + h*64 + d
__global__ void k_pack_qkv(const float* __restrict__ Wq, const float* __restrict__ Wk,
                           const float* __restrict__ Wv, unsigned short* __restrict__ Wt) {
    int ct = blockIdx.x;           // c tile 0..15
    int wh = blockIdx.y;           // 0..47
    int which = wh >> 4, h = wh & 15;
    const float* src = (which == 0 ? Wq : which == 1 ? Wk : Wv) + (size_t)h * C_ * D_ + (size_t)ct * 64 * D_;
    unsigned short* dst = Wt + (size_t)(which * C_ + h * D_) * C_ + ct * 64;
    transpose_tile64(src, D_, dst, C_);
}

// Wp [H*D][C] fp32 -> Wt[c][hd] bf16
__global__ void k_pack_wp(const float* __restrict__ Wp, unsigned short* __restrict__ Wt) {
    int ct = blockIdx.x;           // src col tile (c)
    int rt = blockIdx.y;           // src row tile (hd)
    const float* src = Wp + (size_t)(rt * 64) * C_ + ct * 64;
    unsigned short* dst = Wt + (size_t)(ct * 64) * (H_ * D_) + rt * 64;
    transpose_tile64(src, C_, dst, H_ * D_);
}

// ---------------- GEMM (m97 structure): C[M][N] = A[M][1024] * Bt[N][1024]^T ----------------
// Staging via global_load_lds width 16, linear LDS [128][64].
// MODE 0: scatter bf16 into q/k/v [B,H,S,D] (q scaled by 0.125).  MODE 1: fp32 out + bias.
template <int MODE>
__global__ __launch_bounds__(256, 2) void k_gemm(
    const unsigned short* __restrict__ A, const unsigned short* __restrict__ Bt,
    float* __restrict__ Cout, const float* __restrict__ bias, int N,
    unsigned short* __restrict__ q_out, unsigned short* __restrict__ k_out,
    unsigned short* __restrict__ v_out) {
    constexpr int KD = 1024, BK = 64;
    __shared__ unsigned short As[128][64];
    __shared__ unsigned short Bs[128][64];

    int tid = threadIdx.x;
    int m0 = blockIdx.x * 128;
    int n0 = blockIdx.y * 128;
    int wave = tid >> 6, lane = tid & 63;
    int lg = lane >> 4, lr = lane & 15;
    int wm = (wave >> 1) * 64, wn = (wave & 1) * 64;

    const unsigned short* Ab = A + (size_t)m0 * KD;
    const unsigned short* Bb = Bt + (size_t)n0 * KD;
    // per-lane staging source offsets: round r, wave w covers rows [(r*4+w)*8, +8)
    const int srow = lane >> 3;           // 0..7 within the 8-row chunk
    const int scol = (lane & 7) * 8;      // shorts

    f32x4 acc[4][4];
#pragma unroll
    for (int i = 0; i < 4; ++i)
#pragma unroll
        for (int j = 0; j < 4; ++j) acc[i][j] = (f32x4){0.f, 0.f, 0.f, 0.f};

    for (int k0 = 0; k0 < KD; k0 += BK) {
#pragma unroll
        for (int r = 0; r < 4; ++r) {
            int rowbase = (r * 4 + wave) * 8;
            gload_lds16(Ab + (size_t)(rowbase + srow) * KD + k0 + scol, &As[rowbase][0]);
            gload_lds16(Bb + (size_t)(rowbase + srow) * KD + k0 + scol, &Bs[rowbase][0]);
        }
        __syncthreads();
#pragma unroll
        for (int kk = 0; kk < 2; ++kk) {
            bf16x8 af[4], bfr[4];
#pragma unroll
            for (int i = 0; i < 4; ++i) {
                af[i]  = *(const bf16x8*)(&As[wm + i * 16 + lr][kk * 32 + lg * 8]);
                bfr[i] = *(const bf16x8*)(&Bs[wn + i * 16 + lr][kk * 32 + lg * 8]);
            }
#pragma unroll
            for (int i = 0; i < 4; ++i)
#pragma unroll
                for (int j = 0; j < 4; ++j)
                    acc[i][j] = MFMA16(af[i], bfr[j], acc[i][j]);
        }
        __syncthreads();
    }

#pragma unroll
    for (int i = 0; i < 4; ++i) {
#pragma unroll
        for (int j = 0; j < 4; ++j) {
            int ncol = n0 + wn + j * 16 + lr;
#pragma unroll
            for (int r = 0; r < 4; ++r) {
                int m = m0 + wm + i * 16 + lg * 4 + r;
                float val = acc[i][j][r];
                if (MODE == 0) {
                    int which = ncol >> 10, rr = ncol & 1023;
                    int h = rr >> 6, d = rr & 63;
                    int b = m >> 11, s = m & 2047;
                    if (which == 0) val *= 0.125f;   // fold attn scale into Q
                    unsigned short* dst = (which == 0 ? q_out : which == 1 ? k_out : v_out);
                    dst[(((size_t)(b * H_ + h)) * S_ + s) * D_ + d] = f2b(val);
                } else {
                    Cout[(size_t)m * N + ncol] = val + bias[ncol];
                }
            }
        }
    }
}

// ---------------- flash attention (causal), 8 warps x 32 q-rows, KVBLK=64 ----------------
// Swapped QK^T: S^T = K*Q^T via mfma_32x32x16 -> lane owns one q column.
// PV as O^T = V^T * P^T -> rescale is lane-local. P never leaves registers.
// Load-balance: block processes qtile pair {x, 7-x} -> uniform 36 tile-passes/block.
__global__ __launch_bounds__(512, 2) void k_attn(
    const unsigned short* __restrict__ Qg, const unsigned short* __restrict__ Kg,
    const unsigned short* __restrict__ Vg, unsigned short* __restrict__ Og) {
    union SMem {
        struct {
            unsigned short k[64][72];     // K natural [t][d], row pad 8
            unsigned short v[4672];       // V^T gap layout: off(d)=d*72+(d>>3)*8, col t
        } st;
        unsigned short oe[8][32][72];     // epilogue O staging per warp
    };
    __shared__ SMem sm;

    const int tid = threadIdx.x;
    const int wid = tid >> 6, lane = tid & 63;
    const int ql = lane & 31, hv = lane >> 5;
    const int bh = blockIdx.y;
    const int b = bh >> 4, hh = bh & 15;
    const unsigned short* Qh = Qg + (size_t)bh * S_ * D_;
    const unsigned short* Kh = Kg + (size_t)bh * S_ * D_;
    const unsigned short* Vh = Vg + (size_t)bh * S_ * D_;

    for (int half = 0; half < 2; ++half) {
        const int qtile = half ? (7 - (int)blockIdx.x) : (int)blockIdx.x;
        const int q0 = qtile * 256;
        const int qw = q0 + wid * 32;
        const int qglob = qw + ql;

        // Q fragments (B-operand): lane ql = q col, k elems d = dk*16 + hv*8 + j
        bf16x8 qf[4];
#pragma unroll
        for (int dk = 0; dk < 4; ++dk)
            qf[dk] = *(const bf16x8*)(Qh + (size_t)(qw + ql) * D_ + dk * 16 + hv * 8);

        f32x16 oacc[2];
#pragma unroll
        for (int i = 0; i < 16; ++i) { oacc[0][i] = 0.f; oacc[1][i] = 0.f; }
        float m2 = NEG, lsum = 0.f;

        const int ntiles = qtile * 4 + 4;
        for (int tc = 0; tc < ntiles; ++tc) {
            const int t0 = tc * 64;
            // ---- stage K natural + V transposed (gap layout) : 512 threads, one pass
            {
                const int row = tid >> 3, part = tid & 7;
                bf16x8 kv = *(const bf16x8*)(Kh + (size_t)(t0 + row) * D_ + part * 8);
                *(bf16x8*)(&sm.st.k[row][part * 8]) = kv;
                bf16x8 vv = *(const bf16x8*)(Vh + (size_t)(t0 + row) * D_ + part * 8);
#pragma unroll
                for (int j = 0; j < 8; ++j) {
                    int d = part * 8 + j;
                    sm.st.v[d * 72 + part * 8 + row] = (unsigned short)vv[j];
                }
            }
            __syncthreads();

            if (t0 < qw + 32) {
                // ---- S^T = K · Q^T  (two 32x32 t-subtiles)
                f32x16 st[2];
#pragma unroll
                for (int ts = 0; ts < 2; ++ts) {
#pragma unroll
                    for (int i = 0; i < 16; ++i) st[ts][i] = 0.f;
#pragma unroll
                    for (int dk = 0; dk < 4; ++dk) {
                        bf16x8 kf = *(const bf16x8*)(&sm.st.k[ts * 32 + ql][dk * 16 + hv * 8]);
                        st[ts] = MFMA32(kf, qf[dk], st[ts]);
                    }
                }
                // ---- online softmax in log2 domain; everything lane-local per q
                const bool diag = (t0 + 63 > qw);
                float z[32];
                float mt = NEG;
#pragma unroll
                for (int ts = 0; ts < 2; ++ts)
#pragma unroll
                    for (int r = 0; r < 16; ++r) {
                        float v = st[ts][r] * L2E;
                        if (diag) {
                            int tg = t0 + ts * 32 + (r & 3) + 8 * (r >> 2) + 4 * hv;
                            if (tg > qglob) v = NEG;
                        }
                        z[ts * 16 + r] = v;
                        mt = fmaxf(mt, v);
                    }
                mt = fmaxf(mt, __shfl_xor(mt, 32));
                float mnew = fmaxf(m2, mt);
                float resc = exp2f(m2 - mnew);
                m2 = mnew;
                float rs = 0.f;
#pragma unroll
                for (int i = 0; i < 32; ++i) {
                    float p = exp2f(z[i] - mnew);
                    z[i] = p;
                    rs += p;
                }
                rs += __shfl_xor(rs, 32);
                lsum = lsum * resc + rs;
#pragma unroll
                for (int i = 0; i < 16; ++i) { oacc[0][i] *= resc; oacc[1][i] *= resc; }

                // ---- P -> bf16 fragments (cvt_pk + lane^32 exchange), then PV
#pragma unroll
                for (int ts = 0; ts < 2; ++ts) {
#pragma unroll
                    for (int sl = 0; sl < 2; ++sl) {
                        unsigned w0, w1, w2, w3;
                        asm("v_cvt_pk_bf16_f32 %0, %1, %2" : "=v"(w0) : "v"(z[ts * 16 + sl * 8 + 0]), "v"(z[ts * 16 + sl * 8 + 1]));
                        asm("v_cvt_pk_bf16_f32 %0, %1, %2" : "=v"(w1) : "v"(z[ts * 16 + sl * 8 + 2]), "v"(z[ts * 16 + sl * 8 + 3]));
                        asm("v_cvt_pk_bf16_f32 %0, %1, %2" : "=v"(w2) : "v"(z[ts * 16 + sl * 8 + 4]), "v"(z[ts * 16 + sl * 8 + 5]));
                        asm("v_cvt_pk_bf16_f32 %0, %1, %2" : "=v"(w3) : "v"(z[ts * 16 + sl * 8 + 6]), "v"(z[ts * 16 + sl * 8 + 7]));
                        unsigned x0 = (unsigned)__shfl_xor((int)w0, 32);
                        unsigned x1 = (unsigned)__shfl_xor((int)w1, 32);
                        unsigned x2 = (unsigned)__shfl_xor((int)w2, 32);
                        unsigned x3 = (unsigned)__shfl_xor((int)w3, 32);
                        i32x4 fw;
                        fw[0] = (int)(hv ? x2 : w0);
                        fw[1] = (int)(hv ? x3 : w1);
                        fw[2] = (int)(hv ? w2 : x0);
                        fw[3] = (int)(hv ? w3 : x1);
                        bf16x8 pf = __builtin_bit_cast(bf16x8, fw);
                        const int slice = ts * 2 + sl;   // 16-wide t slice within KV tile
#pragma unroll
                        for (int dt = 0; dt < 2; ++dt) {
                            int d = dt * 32 + ql;
                            bf16x8 vf = *(const bf16x8*)(&sm.st.v[d * 72 + (d >> 3) * 8 + slice * 16 + hv * 8]);
                            oacc[dt] = MFMA32(vf, pf, oacc[dt]);
                        }
                    }
                }
            }
            __syncthreads();
        }

        // ---- epilogue: O^T regs -> LDS -> coalesced global store [B,S,H*D]
        float inv = 1.f / lsum;
#pragma unroll
        for (int dt = 0; dt < 2; ++dt)
#pragma unroll
            for (int r = 0; r < 16; ++r) {
                int d = dt * 32 + (r & 3) + 8 * (r >> 2) + 4 * hv;
                sm.oe[wid][ql][d] = f2b(oacc[dt][r] * inv);
            }
        __syncthreads();
        {
            const int r = tid >> 1, hlf = tid & 1;
            const int w = r >> 5, q = r & 31;
            unsigned short* dst = Og + ((size_t)(b * S_ + q0 + r)) * (H_ * D_) + hh * D_ + hlf * 32;
#pragma unroll
            for (int i = 0; i < 4; ++i) {
                bf16x8 v = *(const bf16x8*)(&sm.oe[w][q][hlf * 32 + i * 8]);
                *(bf16x8*)(dst + i * 8) = v;
            }
        }
        __syncthreads();   // sm.oe aliases sm.st; protect next half's staging
    }
}

// ---------------- launcher ----------------
extern "C" void kernel_launch(void* const* d_in, const int* in_sizes, int n_in,
                              void* d_out, int out_size, void* d_ws, size_t ws_size,
                              hipStream_t stream) {
    const float* x  = (const float*)d_in[0];
    const float* Wq = (const float*)d_in[1];
    const float* Wk = (const float*)d_in[2];
    const float* Wv = (const float*)d_in[3];
    const float* Wp = (const float*)d_in[4];
    const float* bp = (const float*)d_in[5];
    float* out = (float*)d_out;

    char* ws = (char*)d_ws;
    size_t off = 0;
    unsigned short* Xbf   = (unsigned short*)(ws + off); off += (size_t)M_ * C_ * 2;        // 16 MB
    unsigned short* Wtqkv = (unsigned short*)(ws + off); off += (size_t)N1_ * C_ * 2;       // 6 MB
    unsigned short* Wtp   = (unsigned short*)(ws + off); off += (size_t)C_ * C_ * 2;        // 2 MB
    unsigned short* Qb    = (unsigned short*)(ws + off); off += (size_t)M_ * C_ * 2;        // 16 MB
    unsigned short* Kb    = (unsigned short*)(ws + off); off += (size_t)M_ * C_ * 2;        // 16 MB
    unsigned short* Vb    = (unsigned short*)(ws + off); off += (size_t)M_ * C_ * 2;        // 16 MB
    unsigned short* AO    = (unsigned short*)(ws + off); off += (size_t)M_ * C_ * 2;        // 16 MB

    k_cvt_x<<<dim3(2048), dim3(256), 0, stream>>>(x, Xbf, M_ * C_ / 4);
    k_pack_qkv<<<dim3(16, 48), dim3(256), 0, stream>>>(Wq, Wk, Wv, Wtqkv);
    k_pack_wp<<<dim3(16, 16), dim3(256), 0, stream>>>(Wp, Wtp);

    k_gemm<0><<<dim3(M_ / 128, N1_ / 128), dim3(256), 0, stream>>>(
        Xbf, Wtqkv, nullptr, nullptr, N1_, Qb, Kb, Vb);

    k_attn<<<dim3(S_ / 256 / 2, B_ * H_), dim3(512), 0, stream>>>(Qb, Kb, Vb, AO);

    k_gemm<1><<<dim3(M_ / 128, C_ / 128), dim3(256), 0, stream>>>(
        AO, Wtp, out, bp, C_, nullptr, nullptr, nullptr);
}

// Round 6
// 267.190 us; speedup vs baseline: 2.1407x; 1.1177x over previous
//
#include <hip/hip_runtime.h>
#include <hip/hip_bf16.h>

typedef __attribute__((ext_vector_type(4))) float f32x4;
typedef __attribute__((ext_vector_type(16))) float f32x16;
typedef __attribute__((ext_vector_type(8))) short bf16x8;
typedef __attribute__((ext_vector_type(4))) int i32x4;

#define MFMA16(a, b, c) __builtin_amdgcn_mfma_f32_16x16x32_bf16(a, b, c, 0, 0, 0)
#define MFMA32(a, b, c) __builtin_amdgcn_mfma_f32_32x32x16_bf16(a, b, c, 0, 0, 0)

constexpr int B_ = 4, S_ = 2048, C_ = 1024, H_ = 16, D_ = 64;
constexpr int M_ = B_ * S_;   // 8192
constexpr int N1_ = 3 * C_;   // 3072
constexpr float NEG = -1e30f;
// Q pre-scale: 1/sqrt(64) * log2(e), folded into GEMM<0> scatter
constexpr float QSCALE = 0.125f * 1.4426950408889634f;

static __device__ __forceinline__ unsigned short f2b(float f) {
    union { float f; unsigned u; } a; a.f = f;
    unsigned r = a.u + 0x7fffu + ((a.u >> 16) & 1u);
    return (unsigned short)(r >> 16);
}

// async global -> LDS, 16 bytes per lane. dst must be wave-uniform; HW adds lane*16.
static __device__ __forceinline__ void gload_lds16(const void* g, void* l) {
    __builtin_amdgcn_global_load_lds(
        (const __attribute__((address_space(1))) unsigned int*)g,
        (__attribute__((address_space(3))) unsigned int*)l, 16, 0, 0);
}

// tree max of 16 (depth 4, max3-fusable)
static __device__ __forceinline__ float tmax16(const f32x16& s) {
    float a0 = fmaxf(s[0], s[8]),  a1 = fmaxf(s[1], s[9]);
    float a2 = fmaxf(s[2], s[10]), a3 = fmaxf(s[3], s[11]);
    float a4 = fmaxf(s[4], s[12]), a5 = fmaxf(s[5], s[13]);
    float a6 = fmaxf(s[6], s[14]), a7 = fmaxf(s[7], s[15]);
    float b0 = fmaxf(a0, a4), b1 = fmaxf(a1, a5);
    float b2 = fmaxf(a2, a6), b3 = fmaxf(a3, a7);
    return fmaxf(fmaxf(b0, b1), fmaxf(b2, b3));
}

// in-place exp2(s - m), returns tree sum
static __device__ __forceinline__ float expsum16(f32x16& s, float m) {
#pragma unroll
    for (int r = 0; r < 16; ++r) s[r] = exp2f(s[r] - m);
    float a0 = s[0] + s[8],  a1 = s[1] + s[9];
    float a2 = s[2] + s[10], a3 = s[3] + s[11];
    float a4 = s[4] + s[12], a5 = s[5] + s[13];
    float a6 = s[6] + s[14], a7 = s[7] + s[15];
    float b0 = a0 + a4, b1 = a1 + a5, b2 = a2 + a6, b3 = a3 + a7;
    return (b0 + b1) + (b2 + b3);
}

// ---------------- x fp32 -> bf16 ----------------
__global__ void k_cvt_x(const float* __restrict__ x, unsigned short* __restrict__ xb, int n4) {
    int i = blockIdx.x * blockDim.x + threadIdx.x;
    int stride = gridDim.x * blockDim.x;
    for (; i < n4; i += stride) {
        float4 v = ((const float4*)x)[i];
        ushort4 o;
        o.x = f2b(v.x); o.y = f2b(v.y); o.z = f2b(v.z); o.w = f2b(v.w);
        ((ushort4*)xb)[i] = o;
    }
}

// ---------------- 64x64 transpose+convert tile ----------------
static __device__ void transpose_tile64(const float* __restrict__ src, int sld,
                                        unsigned short* __restrict__ dst, int dld) {
    __shared__ unsigned short T[64][68];
    int tid = threadIdx.x;
#pragma unroll
    for (int rep = 0; rep < 4; ++rep) {
        int r = rep * 16 + (tid >> 4);
        int c = (tid & 15) * 4;
        float4 v = *(const float4*)(src + r * sld + c);
        T[c + 0][r] = f2b(v.x);
        T[c + 1][r] = f2b(v.y);
        T[c + 2][r] = f2b(v.z);
        T[c + 3][r] = f2b(v.w);
    }
    __syncthreads();
#pragma unroll
    for (int rep = 0; rep < 4; ++rep) {
        int r = rep * 16 + (tid >> 4);
        int c = (tid & 15) * 4;
        ushort4 o = *(const ushort4*)(&T[r][c]);
        *(ushort4*)(dst + r * dld + c) = o;
    }
}

// Wq/Wk/Wv [H][C][D] fp32  ->  Wt[n][c] bf16, n = which*1024 + h*64 + d
__global__ void k_pack_qkv(const float* __restrict__ Wq, const float* __restrict__ Wk,
                           const float* __restrict__ Wv, unsigned short* __restrict__ Wt) {
    int ct = blockIdx.x;           // c tile 0..15
    int wh = blockIdx.y;           // 0..47
    int which = wh >> 4, h = wh & 15;
    const float* src = (which == 0 ? Wq : which == 1 ? Wk : Wv) + (size_t)h * C_ * D_ + (size_t)ct * 64 * D_;
    unsigned short* dst = Wt + (size_t)(which * C_ + h * D_) * C_ + ct * 64;
    transpose_tile64(src, D_, dst, C_);
}

// Wp [H*D][C] fp32 -> Wt[c][hd] bf16
__global__ void k_pack_wp(const float* __restrict__ Wp, unsigned short* __restrict__ Wt) {
    int ct = blockIdx.x;           // src col tile (c)
    int rt = blockIdx.y;           // src row tile (hd)
    const float* src = Wp + (size_t)(rt * 64) * C_ + ct * 64;
    unsigned short* dst = Wt + (size_t)(ct * 64) * (H_ * D_) + rt * 64;
    transpose_tile64(src, C_, dst, H_ * D_);
}

// ---------------- GEMM (m97 structure): C[M][N] = A[M][1024] * Bt[N][1024]^T ----------------
// Staging via global_load_lds width 16, linear LDS [128][64].
// MODE 0: scatter bf16 into q/k/v [B,H,S,D] (q scaled by QSCALE).  MODE 1: fp32 out + bias.
template <int MODE>
__global__ __launch_bounds__(256, 2) void k_gemm(
    const unsigned short* __restrict__ A, const unsigned short* __restrict__ Bt,
    float* __restrict__ Cout, const float* __restrict__ bias, int N,
    unsigned short* __restrict__ q_out, unsigned short* __restrict__ k_out,
    unsigned short* __restrict__ v_out) {
    constexpr int KD = 1024, BK = 64;
    __shared__ unsigned short As[128][64];
    __shared__ unsigned short Bs[128][64];

    int tid = threadIdx.x;
    int m0 = blockIdx.x * 128;
    int n0 = blockIdx.y * 128;
    int wave = tid >> 6, lane = tid & 63;
    int lg = lane >> 4, lr = lane & 15;
    int wm = (wave >> 1) * 64, wn = (wave & 1) * 64;

    const unsigned short* Ab = A + (size_t)m0 * KD;
    const unsigned short* Bb = Bt + (size_t)n0 * KD;
    // per-lane staging source offsets: round r, wave w covers rows [(r*4+w)*8, +8)
    const int srow = lane >> 3;           // 0..7 within the 8-row chunk
    const int scol = (lane & 7) * 8;      // shorts

    f32x4 acc[4][4];
#pragma unroll
    for (int i = 0; i < 4; ++i)
#pragma unroll
        for (int j = 0; j < 4; ++j) acc[i][j] = (f32x4){0.f, 0.f, 0.f, 0.f};

    for (int k0 = 0; k0 < KD; k0 += BK) {
#pragma unroll
        for (int r = 0; r < 4; ++r) {
            int rowbase = (r * 4 + wave) * 8;
            gload_lds16(Ab + (size_t)(rowbase + srow) * KD + k0 + scol, &As[rowbase][0]);
            gload_lds16(Bb + (size_t)(rowbase + srow) * KD + k0 + scol, &Bs[rowbase][0]);
        }
        __syncthreads();
#pragma unroll
        for (int kk = 0; kk < 2; ++kk) {
            bf16x8 af[4], bfr[4];
#pragma unroll
            for (int i = 0; i < 4; ++i) {
                af[i]  = *(const bf16x8*)(&As[wm + i * 16 + lr][kk * 32 + lg * 8]);
                bfr[i] = *(const bf16x8*)(&Bs[wn + i * 16 + lr][kk * 32 + lg * 8]);
            }
#pragma unroll
            for (int i = 0; i < 4; ++i)
#pragma unroll
                for (int j = 0; j < 4; ++j)
                    acc[i][j] = MFMA16(af[i], bfr[j], acc[i][j]);
        }
        __syncthreads();
    }

#pragma unroll
    for (int i = 0; i < 4; ++i) {
#pragma unroll
        for (int j = 0; j < 4; ++j) {
            int ncol = n0 + wn + j * 16 + lr;
#pragma unroll
            for (int r = 0; r < 4; ++r) {
                int m = m0 + wm + i * 16 + lg * 4 + r;
                float val = acc[i][j][r];
                if (MODE == 0) {
                    int which = ncol >> 10, rr = ncol & 1023;
                    int h = rr >> 6, d = rr & 63;
                    int b = m >> 11, s = m & 2047;
                    if (which == 0) val *= QSCALE;   // fold attn scale + log2e into Q
                    unsigned short* dst = (which == 0 ? q_out : which == 1 ? k_out : v_out);
                    dst[(((size_t)(b * H_ + h)) * S_ + s) * D_ + d] = f2b(val);
                } else {
                    Cout[(size_t)m * N + ncol] = val + bias[ncol];
                }
            }
        }
    }
}

// ---------------- flash attention (causal), 8 warps x 32 q-rows, KVBLK=64 ----------------
// Swapped QK^T: S^T = K*Q^T via mfma_32x32x16 -> lane owns one q column.
// PV as O^T = V^T * P^T -> rescale is lane-local. P never leaves registers.
// qtile pairing {x, 7-x}: uniform 36 passes/block.
// Double-buffered LDS staging (1 barrier/pass); defer-max (thr=8 log2) skips O rescale.
__global__ __launch_bounds__(512, 2) void k_attn(
    const unsigned short* __restrict__ Qg, const unsigned short* __restrict__ Kg,
    const unsigned short* __restrict__ Vg, unsigned short* __restrict__ Og) {
    struct Tile {
        unsigned short k[64][72];     // K natural [t][d], row pad 8
        unsigned short v[4672];       // V^T gap layout: off(d)=d*72+(d>>3)*8, col t
    };
    union SMem {
        Tile st[2];                   // double buffer
        unsigned short oe[8][32][72]; // epilogue O staging per warp
    };
    __shared__ SMem sm;

    const int tid = threadIdx.x;
    const int wid = tid >> 6, lane = tid & 63;
    const int ql = lane & 31, hv = lane >> 5;
    const int bh = blockIdx.y;
    const int b = bh >> 4, hh = bh & 15;
    const unsigned short* Qh = Qg + (size_t)bh * S_ * D_;
    const unsigned short* Kh = Kg + (size_t)bh * S_ * D_;
    const unsigned short* Vh = Vg + (size_t)bh * S_ * D_;
    const int srow = tid >> 3, spart = tid & 7;   // staging: row, 16B-part

    for (int half = 0; half < 2; ++half) {
        const int qtile = half ? (7 - (int)blockIdx.x) : (int)blockIdx.x;
        const int q0 = qtile * 256;
        const int qw = q0 + wid * 32;
        const int qglob = qw + ql;

        // Q fragments (B-operand): lane ql = q col, k elems d = dk*16 + hv*8 + j
        bf16x8 qf[4];
#pragma unroll
        for (int dk = 0; dk < 4; ++dk)
            qf[dk] = *(const bf16x8*)(Qh + (size_t)(qw + ql) * D_ + dk * 16 + hv * 8);

        f32x16 oacc0, oacc1;
#pragma unroll
        for (int i = 0; i < 16; ++i) { oacc0[i] = 0.f; oacc1[i] = 0.f; }
        float m2 = NEG, lsum = 0.f;

        const int ntiles = qtile * 4 + 4;
        // prologue: load tile 0 into registers
        bf16x8 kreg = *(const bf16x8*)(Kh + (size_t)srow * D_ + spart * 8);
        bf16x8 vreg = *(const bf16x8*)(Vh + (size_t)srow * D_ + spart * 8);

        for (int tc = 0; tc < ntiles; ++tc) {
            const int t0 = tc * 64;
            Tile* S = &sm.st[tc & 1];
            // ---- write staged regs to LDS (K vector, V scalar-transposed gap layout)
            *(bf16x8*)(&S->k[srow][spart * 8]) = kreg;
#pragma unroll
            for (int j = 0; j < 8; ++j)
                S->v[(spart * 8 + j) * 72 + spart * 8 + srow] = (unsigned short)vreg[j];
            __syncthreads();
            // ---- issue next tile's global loads (latency hides under compute)
            if (tc + 1 < ntiles) {
                kreg = *(const bf16x8*)(Kh + (size_t)(t0 + 64 + srow) * D_ + spart * 8);
                vreg = *(const bf16x8*)(Vh + (size_t)(t0 + 64 + srow) * D_ + spart * 8);
            }

            if (t0 < qw + 32) {
                // ---- S^T = K · Q^T  (two 32x32 t-subtiles)
                f32x16 st0, st1;
#pragma unroll
                for (int i = 0; i < 16; ++i) { st0[i] = 0.f; st1[i] = 0.f; }
#pragma unroll
                for (int dk = 0; dk < 4; ++dk) {
                    bf16x8 kf0 = *(const bf16x8*)(&S->k[ql][dk * 16 + hv * 8]);
                    st0 = MFMA32(kf0, qf[dk], st0);
                }
#pragma unroll
                for (int dk = 0; dk < 4; ++dk) {
                    bf16x8 kf1 = *(const bf16x8*)(&S->k[32 + ql][dk * 16 + hv * 8]);
                    st1 = MFMA32(kf1, qf[dk], st1);
                }
                // ---- causal mask (diag tiles only); scores already in log2 domain
                if (t0 + 63 > qw) {
                    const int base = t0 + 4 * hv;
#pragma unroll
                    for (int r = 0; r < 16; ++r) {
                        int tg = base + (r & 3) + 8 * (r >> 2);
                        if (tg > qglob) st0[r] = NEG;
                        if (tg + 32 > qglob) st1[r] = NEG;
                    }
                }
                // ---- online softmax with defer-max (thr = 8 in log2 units)
                float mt = fmaxf(tmax16(st0), tmax16(st1));
                mt = fmaxf(mt, __shfl_xor(mt, 32));
                if (!__all(mt - m2 <= 8.0f)) {
                    float mn = fmaxf(m2, mt);
                    float rc = exp2f(m2 - mn);
                    m2 = mn;
                    lsum *= rc;
#pragma unroll
                    for (int i = 0; i < 16; ++i) { oacc0[i] *= rc; oacc1[i] *= rc; }
                }
                float rs = expsum16(st0, m2) + expsum16(st1, m2);
                rs += __shfl_xor(rs, 32);
                lsum += rs;

                // ---- P -> bf16 fragments (cvt_pk + lane^32 exchange), then PV
#pragma unroll
                for (int ts = 0; ts < 2; ++ts) {
                    const f32x16& zz = ts ? st1 : st0;
#pragma unroll
                    for (int sl = 0; sl < 2; ++sl) {
                        unsigned w0, w1, w2, w3;
                        asm("v_cvt_pk_bf16_f32 %0, %1, %2" : "=v"(w0) : "v"(zz[sl * 8 + 0]), "v"(zz[sl * 8 + 1]));
                        asm("v_cvt_pk_bf16_f32 %0, %1, %2" : "=v"(w1) : "v"(zz[sl * 8 + 2]), "v"(zz[sl * 8 + 3]));
                        asm("v_cvt_pk_bf16_f32 %0, %1, %2" : "=v"(w2) : "v"(zz[sl * 8 + 4]), "v"(zz[sl * 8 + 5]));
                        asm("v_cvt_pk_bf16_f32 %0, %1, %2" : "=v"(w3) : "v"(zz[sl * 8 + 6]), "v"(zz[sl * 8 + 7]));
                        unsigned x0 = (unsigned)__shfl_xor((int)w0, 32);
                        unsigned x1 = (unsigned)__shfl_xor((int)w1, 32);
                        unsigned x2 = (unsigned)__shfl_xor((int)w2, 32);
                        unsigned x3 = (unsigned)__shfl_xor((int)w3, 32);
                        i32x4 fw;
                        fw[0] = (int)(hv ? x2 : w0);
                        fw[1] = (int)(hv ? x3 : w1);
                        fw[2] = (int)(hv ? w2 : x0);
                        fw[3] = (int)(hv ? w3 : x1);
                        bf16x8 pf = __builtin_bit_cast(bf16x8, fw);
                        const int slice = ts * 2 + sl;   // 16-wide t slice within KV tile
                        {
                            int d = ql;
                            bf16x8 vf = *(const bf16x8*)(&S->v[d * 72 + (d >> 3) * 8 + slice * 16 + hv * 8]);
                            oacc0 = MFMA32(vf, pf, oacc0);
                        }
                        {
                            int d = 32 + ql;
                            bf16x8 vf = *(const bf16x8*)(&S->v[d * 72 + (d >> 3) * 8 + slice * 16 + hv * 8]);
                            oacc1 = MFMA32(vf, pf, oacc1);
                        }
                    }
                }
            }
            // no trailing barrier: next pass writes the OTHER buffer; the barrier
            // inside pass tc+1 gates the write of pass tc+2 (same buffer as tc).
        }
        __syncthreads();   // all compute done before oe (aliases st) is written

        // ---- epilogue: O^T regs -> LDS -> coalesced global store [B,S,H*D]
        float inv = 1.f / lsum;
#pragma unroll
        for (int r = 0; r < 16; ++r) {
            int d = (r & 3) + 8 * (r >> 2) + 4 * hv;
            sm.oe[wid][ql][d] = f2b(oacc0[r] * inv);
            sm.oe[wid][ql][32 + d] = f2b(oacc1[r] * inv);
        }
        __syncthreads();
        {
            const int r = tid >> 1, hlf = tid & 1;
            const int w = r >> 5, q = r & 31;
            unsigned short* dst = Og + ((size_t)(b * S_ + q0 + r)) * (H_ * D_) + hh * D_ + hlf * 32;
#pragma unroll
            for (int i = 0; i < 4; ++i) {
                bf16x8 v = *(const bf16x8*)(&sm.oe[w][q][hlf * 32 + i * 8]);
                *(bf16x8*)(dst + i * 8) = v;
            }
        }
        __syncthreads();   // oe aliases st; protect next half's staging
    }
}

// ---------------- launcher ----------------
extern "C" void kernel_launch(void* const* d_in, const int* in_sizes, int n_in,
                              void* d_out, int out_size, void* d_ws, size_t ws_size,
                              hipStream_t stream) {
    const float* x  = (const float*)d_in[0];
    const float* Wq = (const float*)d_in[1];
    const float* Wk = (const float*)d_in[2];
    const float* Wv = (const float*)d_in[3];
    const float* Wp = (const float*)d_in[4];
    const float* bp = (const float*)d_in[5];
    float* out = (float*)d_out;

    char* ws = (char*)d_ws;
    size_t off = 0;
    unsigned short* Xbf   = (unsigned short*)(ws + off); off += (size_t)M_ * C_ * 2;        // 16 MB
    unsigned short* Wtqkv = (unsigned short*)(ws + off); off += (size_t)N1_ * C_ * 2;       // 6 MB
    unsigned short* Wtp   = (unsigned short*)(ws + off); off += (size_t)C_ * C_ * 2;        // 2 MB
    unsigned short* Qb    = (unsigned short*)(ws + off); off += (size_t)M_ * C_ * 2;        // 16 MB
    unsigned short* Kb    = (unsigned short*)(ws + off); off += (size_t)M_ * C_ * 2;        // 16 MB
    unsigned short* Vb    = (unsigned short*)(ws + off); off += (size_t)M_ * C_ * 2;        // 16 MB
    unsigned short* AO    = (unsigned short*)(ws + off); off += (size_t)M_ * C_ * 2;        // 16 MB

    k_cvt_x<<<dim3(2048), dim3(256), 0, stream>>>(x, Xbf, M_ * C_ / 4);
    k_pack_qkv<<<dim3(16, 48), dim3(256), 0, stream>>>(Wq, Wk, Wv, Wtqkv);
    k_pack_wp<<<dim3(16, 16), dim3(256), 0, stream>>>(Wp, Wtp);

    k_gemm<0><<<dim3(M_ / 128, N1_ / 128), dim3(256), 0, stream>>>(
        Xbf, Wtqkv, nullptr, nullptr, N1_, Qb, Kb, Vb);

    k_attn<<<dim3(S_ / 256 / 2, B_ * H_), dim3(512), 0, stream>>>(Qb, Kb, Vb, AO);

    k_gemm<1><<<dim3(M_ / 128, C_ / 128), dim3(256), 0, stream>>>(
        AO, Wtp, out, bp, C_, nullptr, nullptr, nullptr);
}